// Round 4
// baseline (168.418 us; speedup 1.0000x reference)
//
#include <hip/hip_runtime.h>
#include <math.h>

// B=2, L=1024, D=1024, H=16, HD=64.
// probs_ij = s_ij*nc_j^-0.5 / sum_j(s_ij*nc_j^-0.5)   (N_R^-0.5 cancels)
// s_ij = (1 + dist_ij/64)^(-65.5), dist from bf16-rounded Q,K.

typedef __attribute__((ext_vector_type(8))) short short8;
typedef __attribute__((ext_vector_type(4))) float f32x4;

__device__ inline unsigned short f2bf(float f) {
  unsigned int u = __float_as_uint(f);
  unsigned int r = (u + 0x7FFFu + ((u >> 16) & 1u)) >> 16;
  return (unsigned short)r;
}
__device__ inline float bf2f(unsigned short s) {
  return __uint_as_float(((unsigned int)s) << 16);
}
__device__ inline float score_fn(float dot, float sq) {
  float d2 = fmaxf(fmaf(-2.f, dot, sq), 1e-12f);
  float g = __builtin_amdgcn_sqrtf(d2) * 0.015625f;   // dist/64
  return __builtin_amdgcn_exp2f(-65.5f * __builtin_amdgcn_logf(1.f + g));
}
// pack two f32 -> one dword of 2 bf16 (RNE), lo = first arg
__device__ inline unsigned int cvtpk(float lo, float hi) {
  unsigned int r;
  asm("v_cvt_pk_bf16_f32 %0, %1, %2" : "=v"(r) : "v"(lo), "v"(hi));
  return r;
}

// ---------------------------------------------------------------------------
__global__ __launch_bounds__(256) void cvt_f32_bf16(const float* __restrict__ in,
                                                    unsigned short* __restrict__ out) {
  int i = blockIdx.x * 256 + threadIdx.x;
  float4 v = ((const float4*)in)[i];
  out[4 * i + 0] = f2bf(v.x);
  out[4 * i + 1] = f2bf(v.y);
  out[4 * i + 2] = f2bf(v.z);
  out[4 * i + 3] = f2bf(v.w);
}

// 4 weight transposes in one launch: W f32 [k][n] -> WT bf16 [n][k]
__global__ __launch_bounds__(256) void wtrans4(const float* __restrict__ W0,
                                               const float* __restrict__ W1,
                                               const float* __restrict__ W2,
                                               const float* __restrict__ W3,
                                               unsigned short* __restrict__ T0,
                                               unsigned short* __restrict__ T1,
                                               unsigned short* __restrict__ T2,
                                               unsigned short* __restrict__ T3) {
  int z = blockIdx.z;
  const float* W = z == 0 ? W0 : z == 1 ? W1 : z == 2 ? W2 : W3;
  unsigned short* WT = z == 0 ? T0 : z == 1 ? T1 : z == 2 ? T2 : T3;
  __shared__ float T[32][33];
  int k0 = blockIdx.x * 32, n0 = blockIdx.y * 32;
  int c = threadIdx.x & 31, r8 = threadIdx.x >> 5;
#pragma unroll
  for (int it = 0; it < 4; ++it) {
    int rr = r8 + it * 8;
    T[rr][c] = W[(size_t)(k0 + rr) * 1024 + n0 + c];
  }
  __syncthreads();
#pragma unroll
  for (int it = 0; it < 4; ++it) {
    int rr = r8 + it * 8;
    WT[(size_t)(n0 + rr) * 1024 + k0 + c] = f2bf(T[c][rr]);
  }
}

// ---------------------------------------------------------------------------
// LDS-staged MFMA GEMM, BM=BN=BK=64, 4 waves, XOR-swizzled 16B chunks.
// mode 0: bf16 head layout [bh][l][64]
// mode 1: bf16 VT-permuted [bh][64][1024]  (k-order permuted per 32-block for
//         direct consumption as PV B-operand against swapped-QK P fragments)
// mode 2: f32 row-major [m][n]
__global__ __launch_bounds__(256) void gemm_st(const unsigned short* __restrict__ A,
                                               const unsigned short* __restrict__ B0,
                                               const unsigned short* __restrict__ B1,
                                               const unsigned short* __restrict__ B2,
                                               const float* __restrict__ c0,
                                               const float* __restrict__ c1,
                                               const float* __restrict__ c2,
                                               void* __restrict__ Y0,
                                               void* __restrict__ Y1,
                                               void* __restrict__ Y2,
                                               int m0, int m1, int m2) {
  int z = blockIdx.z;
  const unsigned short* BT = z == 0 ? B0 : z == 1 ? B1 : B2;
  const float* bias = z == 0 ? c0 : z == 1 ? c1 : c2;
  void* Y = z == 0 ? Y0 : z == 1 ? Y1 : Y2;
  int mode = z == 0 ? m0 : z == 1 ? m1 : m2;

  __shared__ __align__(16) unsigned short As[64 * 64];
  __shared__ __align__(16) unsigned short Bs[64 * 64];
  int tid = threadIdx.x;
  int w = tid >> 6, l = tid & 63, g = l >> 4, l15 = l & 15;
  int bm = blockIdx.x * 64, bn = blockIdx.y * 64;

  int sr = tid >> 2;
  int sj = (tid & 3) * 2;
  int sw0 = (sj ^ (sr & 7)) * 8;
  int sw1 = ((sj + 1) ^ (sr & 7)) * 8;
  const int arow = w * 16 + l15;

  f32x4 acc[4];
#pragma unroll
  for (int t = 0; t < 4; ++t)
#pragma unroll
    for (int r = 0; r < 4; ++r) acc[t][r] = 0.f;

  for (int k0 = 0; k0 < 1024; k0 += 64) {
    short8 av0 = *(const short8*)&A[(size_t)(bm + sr) * 1024 + k0 + sj * 8];
    short8 av1 = *(const short8*)&A[(size_t)(bm + sr) * 1024 + k0 + sj * 8 + 8];
    short8 bv0 = *(const short8*)&BT[(size_t)(bn + sr) * 1024 + k0 + sj * 8];
    short8 bv1 = *(const short8*)&BT[(size_t)(bn + sr) * 1024 + k0 + sj * 8 + 8];
    __syncthreads();
    *(short8*)&As[sr * 64 + sw0] = av0;
    *(short8*)&As[sr * 64 + sw1] = av1;
    *(short8*)&Bs[sr * 64 + sw0] = bv0;
    *(short8*)&Bs[sr * 64 + sw1] = bv1;
    __syncthreads();
#pragma unroll
    for (int kc = 0; kc < 2; ++kc) {
      short8 a = *(const short8*)&As[arow * 64 + ((kc * 4 + g) ^ (arow & 7)) * 8];
#pragma unroll
      for (int t = 0; t < 4; ++t) {
        int brow = t * 16 + l15;
        short8 b = *(const short8*)&Bs[brow * 64 + ((kc * 4 + g) ^ (brow & 7)) * 8];
        acc[t] = __builtin_amdgcn_mfma_f32_16x16x32_bf16(a, b, acc[t], 0, 0, 0);
      }
    }
  }

#pragma unroll
  for (int t = 0; t < 4; ++t) {
    int n = bn + 16 * t + l15;
    float bv = bias[n];
#pragma unroll
    for (int r = 0; r < 4; ++r) {
      int m = bm + w * 16 + 4 * g + r;
      float v = acc[t][r] + bv;
      if (mode == 0) {
        int b = m >> 10, ll = m & 1023, h = n >> 6, hd = n & 63;
        ((unsigned short*)Y)[(((size_t)(b * 16 + h) * 1024) + ll) * 64 + hd] = f2bf(v);
      } else if (mode == 1) {
        int b = m >> 10, ll = m & 1023, h = n >> 6, hd = n & 63;
        // permuted k-position within each 32-block: p = 8*g' + 4*jj + r
        int jp = (ll & ~31) | (((ll >> 2) & 3) * 8 + ((ll >> 4) & 1) * 4 + (ll & 3));
        ((unsigned short*)Y)[(((size_t)(b * 16 + h) * 64) + hd) * 1024 + jp] = f2bf(v);
      } else {
        ((float*)Y)[(size_t)m * 1024 + n] = v;
      }
    }
  }
}

// ---------------------------------------------------------------------------
__global__ __launch_bounds__(256) void sqnorm(const unsigned short* __restrict__ Qb,
                                              const unsigned short* __restrict__ Kb,
                                              float* __restrict__ q2,
                                              float* __restrict__ k2) {
  int row = blockIdx.x * 256 + threadIdx.x;
  const unsigned short* src = blockIdx.y ? Kb : Qb;
  float* dst = blockIdx.y ? k2 : q2;
  const short8* p = (const short8*)&src[(size_t)row * 64];
  float s = 0.f;
#pragma unroll
  for (int c = 0; c < 8; ++c) {
    short8 v = p[c];
#pragma unroll
    for (int e = 0; e < 8; ++e) {
      float f = bf2f((unsigned short)v[e]);
      s = fmaf(f, f, s);
    }
  }
  dst[row] = s;
}

// ---------------------------------------------------------------------------
// Pass A: column sums -> rnc = colsum^-0.5.
// grid (32 bh, 64 jt16); block owns 16 cols; wave w sums rows w*256..+255.
__global__ __launch_bounds__(256) void colsum_mfma(const unsigned short* __restrict__ Qb,
                                                   const unsigned short* __restrict__ Kb,
                                                   const float* __restrict__ q2,
                                                   const float* __restrict__ k2,
                                                   float* __restrict__ rnc) {
  __shared__ float red[4][16];
  int bh = blockIdx.x, jt = blockIdx.y;
  int tid = threadIdx.x, w = tid >> 6, l = tid & 63;
  int g = l >> 4, l15 = l & 15;
  const size_t hb = (size_t)bh * 1024;
  int j = jt * 16 + l15;

  short8 bk0 = *(const short8*)&Kb[(hb + j) * 64 + 8 * g];
  short8 bk1 = *(const short8*)&Kb[(hb + j) * 64 + 32 + 8 * g];
  float k2j = k2[hb + j];
  float colacc = 0.f;

  for (int s = 0; s < 8; ++s) {
    int i0 = w * 256 + s * 32;
    short8 a0 = *(const short8*)&Qb[(hb + i0 + l15) * 64 + 8 * g];
    short8 a1 = *(const short8*)&Qb[(hb + i0 + l15) * 64 + 32 + 8 * g];
    short8 a2 = *(const short8*)&Qb[(hb + i0 + 16 + l15) * 64 + 8 * g];
    short8 a3 = *(const short8*)&Qb[(hb + i0 + 16 + l15) * 64 + 32 + 8 * g];
    f32x4 ca, cb;
#pragma unroll
    for (int r = 0; r < 4; ++r) { ca[r] = 0.f; cb[r] = 0.f; }
    ca = __builtin_amdgcn_mfma_f32_16x16x32_bf16(a0, bk0, ca, 0, 0, 0);
    ca = __builtin_amdgcn_mfma_f32_16x16x32_bf16(a1, bk1, ca, 0, 0, 0);
    cb = __builtin_amdgcn_mfma_f32_16x16x32_bf16(a2, bk0, cb, 0, 0, 0);
    cb = __builtin_amdgcn_mfma_f32_16x16x32_bf16(a3, bk1, cb, 0, 0, 0);
    float4 qv = *(const float4*)&q2[hb + i0 + 4 * g];
    float4 qv2 = *(const float4*)&q2[hb + i0 + 16 + 4 * g];
    colacc += score_fn(ca[0], qv.x + k2j);
    colacc += score_fn(ca[1], qv.y + k2j);
    colacc += score_fn(ca[2], qv.z + k2j);
    colacc += score_fn(ca[3], qv.w + k2j);
    colacc += score_fn(cb[0], qv2.x + k2j);
    colacc += score_fn(cb[1], qv2.y + k2j);
    colacc += score_fn(cb[2], qv2.z + k2j);
    colacc += score_fn(cb[3], qv2.w + k2j);
  }
  colacc += __shfl_xor(colacc, 16);
  colacc += __shfl_xor(colacc, 32);
  if (l < 16) red[w][l] = colacc;
  __syncthreads();
  if (tid < 16) {
    float s = red[0][tid] + red[1][tid] + red[2][tid] + red[3][tid];
    rnc[hb + jt * 16 + tid] = __builtin_amdgcn_rsqf(s);
  }
}

// ---------------------------------------------------------------------------
// Pass B (swapped QK): per wave, lane l15 = query row i; j = j0 + 16*jj + 4*g + r.
// P stays in registers as the PV A-fragment (k-order matched by permuted VTp).
// grid (32 bh, 64 it16); 4 waves = 4 j-quarters; LDS merge at end.
__global__ __launch_bounds__(256, 4) void attn_mfma(const unsigned short* __restrict__ Qb,
                                                    const unsigned short* __restrict__ Kb,
                                                    const unsigned short* __restrict__ VTp,
                                                    const float* __restrict__ q2,
                                                    const float* __restrict__ k2,
                                                    const float* __restrict__ rnc,
                                                    unsigned short* __restrict__ AO) {
  __shared__ float Ls[4][64][17];
  __shared__ float Ds[4][16];
  int bh = blockIdx.x;
  int tid = threadIdx.x, w = tid >> 6, l = tid & 63;
  int g = l >> 4, l15 = l & 15;
  int it0 = blockIdx.y * 16;
  const size_t hb = (size_t)bh * 1024;
  int b = bh >> 4, h = bh & 15;

  // Q as B-operand (n = i), fixed for the whole kernel
  short8 bq0 = *(const short8*)&Qb[(hb + it0 + l15) * 64 + 8 * g];
  short8 bq1 = *(const short8*)&Qb[(hb + it0 + l15) * 64 + 32 + 8 * g];
  float q2l = q2[hb + it0 + l15];

  f32x4 o[4];
#pragma unroll
  for (int t = 0; t < 4; ++t)
#pragma unroll
    for (int r = 0; r < 4; ++r) o[t][r] = 0.f;
  float dacc = 0.f;

  for (int c = 0; c < 8; ++c) {
    int j0 = w * 256 + c * 32;
    // K rows as A-operand (m = j)
    short8 ak00 = *(const short8*)&Kb[(hb + j0 + l15) * 64 + 8 * g];
    short8 ak01 = *(const short8*)&Kb[(hb + j0 + l15) * 64 + 32 + 8 * g];
    short8 ak10 = *(const short8*)&Kb[(hb + j0 + 16 + l15) * 64 + 8 * g];
    short8 ak11 = *(const short8*)&Kb[(hb + j0 + 16 + l15) * 64 + 32 + 8 * g];
    f32x4 c0, c1;
#pragma unroll
    for (int r = 0; r < 4; ++r) { c0[r] = 0.f; c1[r] = 0.f; }
    c0 = __builtin_amdgcn_mfma_f32_16x16x32_bf16(ak00, bq0, c0, 0, 0, 0);
    c0 = __builtin_amdgcn_mfma_f32_16x16x32_bf16(ak01, bq1, c0, 0, 0, 0);
    c1 = __builtin_amdgcn_mfma_f32_16x16x32_bf16(ak10, bq0, c1, 0, 0, 0);
    c1 = __builtin_amdgcn_mfma_f32_16x16x32_bf16(ak11, bq1, c1, 0, 0, 0);

    float4 k20 = *(const float4*)&k2[hb + j0 + 4 * g];
    float4 rn0 = *(const float4*)&rnc[hb + j0 + 4 * g];
    float4 k21 = *(const float4*)&k2[hb + j0 + 16 + 4 * g];
    float4 rn1 = *(const float4*)&rnc[hb + j0 + 16 + 4 * g];

    float s0 = score_fn(c0[0], q2l + k20.x) * rn0.x;
    float s1 = score_fn(c0[1], q2l + k20.y) * rn0.y;
    float s2 = score_fn(c0[2], q2l + k20.z) * rn0.z;
    float s3 = score_fn(c0[3], q2l + k20.w) * rn0.w;
    float s4 = score_fn(c1[0], q2l + k21.x) * rn1.x;
    float s5 = score_fn(c1[1], q2l + k21.y) * rn1.y;
    float s6 = score_fn(c1[2], q2l + k21.z) * rn1.z;
    float s7 = score_fn(c1[3], q2l + k21.w) * rn1.w;
    dacc += ((s0 + s1) + (s2 + s3)) + ((s4 + s5) + (s6 + s7));

    int pi[4];
    pi[0] = (int)cvtpk(s0, s1);
    pi[1] = (int)cvtpk(s2, s3);
    pi[2] = (int)cvtpk(s4, s5);
    pi[3] = (int)cvtpk(s6, s7);
    short8 pa = *(short8*)pi;

#pragma unroll
    for (int t = 0; t < 4; ++t) {
      short8 bv = *(const short8*)&VTp[((size_t)bh * 64 + 16 * t + l15) * 1024 + j0 + 8 * g];
      o[t] = __builtin_amdgcn_mfma_f32_16x16x32_bf16(pa, bv, o[t], 0, 0, 0);
    }
  }

  // rowsum for row l15 over this wave's j-quarter
  dacc += __shfl_xor(dacc, 16);
  dacc += __shfl_xor(dacc, 32);
  if (l < 16) Ds[w][l] = dacc;
#pragma unroll
  for (int t = 0; t < 4; ++t)
#pragma unroll
    for (int r = 0; r < 4; ++r) Ls[w][l][t * 4 + r] = o[t][r];
  __syncthreads();

  // wave w finalizes d-tile t = w
  float ov[4], dv[4];
#pragma unroll
  for (int r = 0; r < 4; ++r) {
    ov[r] = o[w][r];
    dv[r] = Ds[0][4 * g + r] + Ds[1][4 * g + r] + Ds[2][4 * g + r] + Ds[3][4 * g + r];
  }
#pragma unroll
  for (int ww = 0; ww < 4; ++ww) {
    if (ww == w) continue;
#pragma unroll
    for (int r = 0; r < 4; ++r) ov[r] += Ls[ww][l][w * 4 + r];
  }
#pragma unroll
  for (int r = 0; r < 4; ++r) {
    int m = b * 1024 + it0 + 4 * g + r;
    int n = h * 64 + w * 16 + l15;
    AO[(size_t)m * 1024 + n] = f2bf(ov[r] / dv[r]);
  }
}

// ---------------------------------------------------------------------------
extern "C" void kernel_launch(void* const* d_in, const int* in_sizes, int n_in,
                              void* d_out, int out_size, void* d_ws, size_t ws_size,
                              hipStream_t stream) {
  const float* x  = (const float*)d_in[0];
  const float* WQ = (const float*)d_in[1];
  const float* bQ = (const float*)d_in[2];
  const float* WK = (const float*)d_in[3];
  const float* bK = (const float*)d_in[4];
  const float* WV = (const float*)d_in[5];
  const float* bV = (const float*)d_in[6];
  const float* WO = (const float*)d_in[7];
  const float* bO = (const float*)d_in[8];

  char* base = (char*)d_ws;
  unsigned short* xb  = (unsigned short*)(base);
  unsigned short* WQT = (unsigned short*)(base + (4u  << 20));
  unsigned short* WKT = (unsigned short*)(base + (6u  << 20));
  unsigned short* WVT = (unsigned short*)(base + (8u  << 20));
  unsigned short* WOT = (unsigned short*)(base + (10u << 20));
  unsigned short* Qb  = (unsigned short*)(base + (12u << 20));
  unsigned short* Kb  = (unsigned short*)(base + (16u << 20));
  unsigned short* VTp = (unsigned short*)(base + (20u << 20));
  unsigned short* AOb = (unsigned short*)(base + (24u << 20));
  float* q2  = (float*)(base + (28u << 20));
  float* k2  = (float*)(base + (28u << 20) + (128u << 10));
  float* rnc = (float*)(base + (28u << 20) + (256u << 10));

  cvt_f32_bf16<<<2048, 256, 0, stream>>>(x, xb);
  wtrans4<<<dim3(32, 32, 4), 256, 0, stream>>>(WQ, WK, WV, WO, WQT, WKT, WVT, WOT);

  // fused Q,K,V projections (V written k-permuted-transposed)
  gemm_st<<<dim3(32, 16, 3), 256, 0, stream>>>(xb, WQT, WKT, WVT, bQ, bK, bV,
                                               Qb, Kb, VTp, 0, 0, 1);

  sqnorm<<<dim3(128, 2), 256, 0, stream>>>(Qb, Kb, q2, k2);
  colsum_mfma<<<dim3(32, 64), 256, 0, stream>>>(Qb, Kb, q2, k2, rnc);
  attn_mfma<<<dim3(32, 64), 256, 0, stream>>>(Qb, Kb, VTp, q2, k2, rnc, AOb);

  // output projection
  gemm_st<<<dim3(32, 16, 1), 256, 0, stream>>>(AOb, WOT, WOT, WOT, bO, bO, bO,
                                               d_out, d_out, d_out, 2, 2, 2);
}

// Round 5
// 159.803 us; speedup vs baseline: 1.0539x; 1.0539x over previous
//
#include <hip/hip_runtime.h>
#include <math.h>

// B=2, L=1024, D=1024, H=16, HD=64.
// probs_ij = s_ij*nc_j^-0.5 / sum_j(s_ij*nc_j^-0.5)   (N_R^-0.5 cancels)
// s_ij = (1 + dist_ij/64)^(-65.5), dist from bf16-rounded Q,K.

typedef __attribute__((ext_vector_type(8))) short short8;
typedef __attribute__((ext_vector_type(4))) float f32x4;

__device__ inline unsigned short f2bf(float f) {
  unsigned int u = __float_as_uint(f);
  unsigned int r = (u + 0x7FFFu + ((u >> 16) & 1u)) >> 16;
  return (unsigned short)r;
}
__device__ inline float bf2f(unsigned short s) {
  return __uint_as_float(((unsigned int)s) << 16);
}
__device__ inline float score_fn(float dot, float sq) {
  float d2 = fmaxf(fmaf(-2.f, dot, sq), 1e-12f);
  float g = __builtin_amdgcn_sqrtf(d2) * 0.015625f;   // dist/64
  return __builtin_amdgcn_exp2f(-65.5f * __builtin_amdgcn_logf(1.f + g));
}
// pack two f32 -> one dword of 2 bf16 (RNE), lo = first arg
__device__ inline unsigned int cvtpk(float lo, float hi) {
  unsigned int r;
  asm("v_cvt_pk_bf16_f32 %0, %1, %2" : "=v"(r) : "v"(lo), "v"(hi));
  return r;
}

// ---------------------------------------------------------------------------
__global__ __launch_bounds__(256) void cvt_f32_bf16(const float* __restrict__ in,
                                                    unsigned short* __restrict__ out) {
  int i = blockIdx.x * 256 + threadIdx.x;
  float4 v = ((const float4*)in)[i];
  out[4 * i + 0] = f2bf(v.x);
  out[4 * i + 1] = f2bf(v.y);
  out[4 * i + 2] = f2bf(v.z);
  out[4 * i + 3] = f2bf(v.w);
}

// 4 weight transposes in one launch: W f32 [k][n] -> WT bf16 [n][k]
__global__ __launch_bounds__(256) void wtrans4(const float* __restrict__ W0,
                                               const float* __restrict__ W1,
                                               const float* __restrict__ W2,
                                               const float* __restrict__ W3,
                                               unsigned short* __restrict__ T0,
                                               unsigned short* __restrict__ T1,
                                               unsigned short* __restrict__ T2,
                                               unsigned short* __restrict__ T3) {
  int z = blockIdx.z;
  const float* W = z == 0 ? W0 : z == 1 ? W1 : z == 2 ? W2 : W3;
  unsigned short* WT = z == 0 ? T0 : z == 1 ? T1 : z == 2 ? T2 : T3;
  __shared__ float T[32][33];
  int k0 = blockIdx.x * 32, n0 = blockIdx.y * 32;
  int c = threadIdx.x & 31, r8 = threadIdx.x >> 5;
#pragma unroll
  for (int it = 0; it < 4; ++it) {
    int rr = r8 + it * 8;
    T[rr][c] = W[(size_t)(k0 + rr) * 1024 + n0 + c];
  }
  __syncthreads();
#pragma unroll
  for (int it = 0; it < 4; ++it) {
    int rr = r8 + it * 8;
    WT[(size_t)(n0 + rr) * 1024 + k0 + c] = f2bf(T[c][rr]);
  }
}

// ---------------------------------------------------------------------------
// LDS-staged MFMA GEMM, BM=BN=BK=64, 4 waves, XOR-swizzled 16B chunks.
// mode 0: bf16 head layout [bh][l][64]
// mode 1: bf16 VT-permuted [bh][64][1024]  (k-order permuted per 32-block)
// mode 2: f32 row-major [m][n]
__global__ __launch_bounds__(256) void gemm_st(const unsigned short* __restrict__ A,
                                               const unsigned short* __restrict__ B0,
                                               const unsigned short* __restrict__ B1,
                                               const unsigned short* __restrict__ B2,
                                               const float* __restrict__ c0,
                                               const float* __restrict__ c1,
                                               const float* __restrict__ c2,
                                               void* __restrict__ Y0,
                                               void* __restrict__ Y1,
                                               void* __restrict__ Y2,
                                               int m0, int m1, int m2) {
  int z = blockIdx.z;
  const unsigned short* BT = z == 0 ? B0 : z == 1 ? B1 : B2;
  const float* bias = z == 0 ? c0 : z == 1 ? c1 : c2;
  void* Y = z == 0 ? Y0 : z == 1 ? Y1 : Y2;
  int mode = z == 0 ? m0 : z == 1 ? m1 : m2;

  __shared__ __align__(16) unsigned short As[64 * 64];
  __shared__ __align__(16) unsigned short Bs[64 * 64];
  int tid = threadIdx.x;
  int w = tid >> 6, l = tid & 63, g = l >> 4, l15 = l & 15;
  int bm = blockIdx.x * 64, bn = blockIdx.y * 64;

  int sr = tid >> 2;
  int sj = (tid & 3) * 2;
  int sw0 = (sj ^ (sr & 7)) * 8;
  int sw1 = ((sj + 1) ^ (sr & 7)) * 8;
  const int arow = w * 16 + l15;

  f32x4 acc[4];
#pragma unroll
  for (int t = 0; t < 4; ++t)
#pragma unroll
    for (int r = 0; r < 4; ++r) acc[t][r] = 0.f;

  for (int k0 = 0; k0 < 1024; k0 += 64) {
    short8 av0 = *(const short8*)&A[(size_t)(bm + sr) * 1024 + k0 + sj * 8];
    short8 av1 = *(const short8*)&A[(size_t)(bm + sr) * 1024 + k0 + sj * 8 + 8];
    short8 bv0 = *(const short8*)&BT[(size_t)(bn + sr) * 1024 + k0 + sj * 8];
    short8 bv1 = *(const short8*)&BT[(size_t)(bn + sr) * 1024 + k0 + sj * 8 + 8];
    __syncthreads();
    *(short8*)&As[sr * 64 + sw0] = av0;
    *(short8*)&As[sr * 64 + sw1] = av1;
    *(short8*)&Bs[sr * 64 + sw0] = bv0;
    *(short8*)&Bs[sr * 64 + sw1] = bv1;
    __syncthreads();
#pragma unroll
    for (int kc = 0; kc < 2; ++kc) {
      short8 a = *(const short8*)&As[arow * 64 + ((kc * 4 + g) ^ (arow & 7)) * 8];
#pragma unroll
      for (int t = 0; t < 4; ++t) {
        int brow = t * 16 + l15;
        short8 b = *(const short8*)&Bs[brow * 64 + ((kc * 4 + g) ^ (brow & 7)) * 8];
        acc[t] = __builtin_amdgcn_mfma_f32_16x16x32_bf16(a, b, acc[t], 0, 0, 0);
      }
    }
  }

#pragma unroll
  for (int t = 0; t < 4; ++t) {
    int n = bn + 16 * t + l15;
    float bv = bias[n];
#pragma unroll
    for (int r = 0; r < 4; ++r) {
      int m = bm + w * 16 + 4 * g + r;
      float v = acc[t][r] + bv;
      if (mode == 0) {
        int b = m >> 10, ll = m & 1023, h = n >> 6, hd = n & 63;
        ((unsigned short*)Y)[(((size_t)(b * 16 + h) * 1024) + ll) * 64 + hd] = f2bf(v);
      } else if (mode == 1) {
        int b = m >> 10, ll = m & 1023, h = n >> 6, hd = n & 63;
        int jp = (ll & ~31) | (((ll >> 2) & 3) * 8 + ((ll >> 4) & 1) * 4 + (ll & 3));
        ((unsigned short*)Y)[(((size_t)(b * 16 + h) * 64) + hd) * 1024 + jp] = f2bf(v);
      } else {
        ((float*)Y)[(size_t)m * 1024 + n] = v;
      }
    }
  }
}

// ---------------------------------------------------------------------------
__global__ __launch_bounds__(256) void sqnorm(const unsigned short* __restrict__ Qb,
                                              const unsigned short* __restrict__ Kb,
                                              float* __restrict__ q2,
                                              float* __restrict__ k2) {
  int row = blockIdx.x * 256 + threadIdx.x;
  const unsigned short* src = blockIdx.y ? Kb : Qb;
  float* dst = blockIdx.y ? k2 : q2;
  const short8* p = (const short8*)&src[(size_t)row * 64];
  float s = 0.f;
#pragma unroll
  for (int c = 0; c < 8; ++c) {
    short8 v = p[c];
#pragma unroll
    for (int e = 0; e < 8; ++e) {
      float f = bf2f((unsigned short)v[e]);
      s = fmaf(f, f, s);
    }
  }
  dst[row] = s;
}

// ---------------------------------------------------------------------------
// Pass A: column sums -> rnc = colsum^-0.5.
// grid (32 bh, 16 jt64); 512 thr. Wave w: cols jt*64+(w&3)*16, i-half (w>>2).
__global__ __launch_bounds__(512) void colsum_mfma(const unsigned short* __restrict__ Qb,
                                                   const unsigned short* __restrict__ Kb,
                                                   const float* __restrict__ q2,
                                                   const float* __restrict__ k2,
                                                   float* __restrict__ rnc) {
  __shared__ float red[8][16];
  int bh = blockIdx.x, jt = blockIdx.y;
  int tid = threadIdx.x, w = tid >> 6, l = tid & 63;
  int g = l >> 4, l15 = l & 15;
  int wq = w & 3, wj = w >> 2;
  const size_t hb = (size_t)bh * 1024;
  int j = jt * 64 + wq * 16 + l15;

  short8 bk0 = *(const short8*)&Kb[(hb + j) * 64 + 8 * g];
  short8 bk1 = *(const short8*)&Kb[(hb + j) * 64 + 32 + 8 * g];
  float k2j = k2[hb + j];
  float colacc = 0.f;

#pragma unroll 2
  for (int s = 0; s < 16; ++s) {
    int i0 = wj * 512 + s * 32;
    short8 a0 = *(const short8*)&Qb[(hb + i0 + l15) * 64 + 8 * g];
    short8 a1 = *(const short8*)&Qb[(hb + i0 + l15) * 64 + 32 + 8 * g];
    short8 a2 = *(const short8*)&Qb[(hb + i0 + 16 + l15) * 64 + 8 * g];
    short8 a3 = *(const short8*)&Qb[(hb + i0 + 16 + l15) * 64 + 32 + 8 * g];
    f32x4 ca, cb;
#pragma unroll
    for (int r = 0; r < 4; ++r) { ca[r] = 0.f; cb[r] = 0.f; }
    ca = __builtin_amdgcn_mfma_f32_16x16x32_bf16(a0, bk0, ca, 0, 0, 0);
    ca = __builtin_amdgcn_mfma_f32_16x16x32_bf16(a1, bk1, ca, 0, 0, 0);
    cb = __builtin_amdgcn_mfma_f32_16x16x32_bf16(a2, bk0, cb, 0, 0, 0);
    cb = __builtin_amdgcn_mfma_f32_16x16x32_bf16(a3, bk1, cb, 0, 0, 0);
    float4 qv = *(const float4*)&q2[hb + i0 + 4 * g];
    float4 qv2 = *(const float4*)&q2[hb + i0 + 16 + 4 * g];
    colacc += score_fn(ca[0], qv.x + k2j);
    colacc += score_fn(ca[1], qv.y + k2j);
    colacc += score_fn(ca[2], qv.z + k2j);
    colacc += score_fn(ca[3], qv.w + k2j);
    colacc += score_fn(cb[0], qv2.x + k2j);
    colacc += score_fn(cb[1], qv2.y + k2j);
    colacc += score_fn(cb[2], qv2.z + k2j);
    colacc += score_fn(cb[3], qv2.w + k2j);
  }
  colacc += __shfl_xor(colacc, 16);
  colacc += __shfl_xor(colacc, 32);
  if (l < 16) red[w][l] = colacc;
  __syncthreads();
  if (tid < 64) {
    float s = red[tid >> 4][tid & 15] + red[(tid >> 4) + 4][tid & 15];
    rnc[hb + jt * 64 + tid] = __builtin_amdgcn_rsqf(s);
  }
}

// ---------------------------------------------------------------------------
// Pass B (swapped QK, register-resident P): grid (32 bh, 16 it64); 512 thr.
// Wave w: q-subtile (w&3) of the block's 64 rows, j-half (w>>2). 2-way merge.
__global__ __launch_bounds__(512) void attn_mfma(const unsigned short* __restrict__ Qb,
                                                 const unsigned short* __restrict__ Kb,
                                                 const unsigned short* __restrict__ VTp,
                                                 const float* __restrict__ q2,
                                                 const float* __restrict__ k2,
                                                 const float* __restrict__ rnc,
                                                 unsigned short* __restrict__ AO) {
  __shared__ float Ls[8][64][17];
  __shared__ float Ds[8][16];
  int bh = blockIdx.x;
  int tid = threadIdx.x, w = tid >> 6, l = tid & 63;
  int g = l >> 4, l15 = l & 15;
  int wq = w & 3, wj = w >> 2;
  int it0 = blockIdx.y * 64 + wq * 16;
  const size_t hb = (size_t)bh * 1024;
  int b = bh >> 4, h = bh & 15;

  // Q as B-operand (n = q-row), fixed for the whole kernel
  short8 bq0 = *(const short8*)&Qb[(hb + it0 + l15) * 64 + 8 * g];
  short8 bq1 = *(const short8*)&Qb[(hb + it0 + l15) * 64 + 32 + 8 * g];
  float q2l = q2[hb + it0 + l15];

  f32x4 o[4];
#pragma unroll
  for (int t = 0; t < 4; ++t)
#pragma unroll
    for (int r = 0; r < 4; ++r) o[t][r] = 0.f;
  float dacc = 0.f;

#pragma unroll 2
  for (int c = 0; c < 16; ++c) {
    int j0 = wj * 512 + c * 32;
    short8 ak00 = *(const short8*)&Kb[(hb + j0 + l15) * 64 + 8 * g];
    short8 ak01 = *(const short8*)&Kb[(hb + j0 + l15) * 64 + 32 + 8 * g];
    short8 ak10 = *(const short8*)&Kb[(hb + j0 + 16 + l15) * 64 + 8 * g];
    short8 ak11 = *(const short8*)&Kb[(hb + j0 + 16 + l15) * 64 + 32 + 8 * g];
    f32x4 c0, c1;
#pragma unroll
    for (int r = 0; r < 4; ++r) { c0[r] = 0.f; c1[r] = 0.f; }
    c0 = __builtin_amdgcn_mfma_f32_16x16x32_bf16(ak00, bq0, c0, 0, 0, 0);
    c0 = __builtin_amdgcn_mfma_f32_16x16x32_bf16(ak01, bq1, c0, 0, 0, 0);
    c1 = __builtin_amdgcn_mfma_f32_16x16x32_bf16(ak10, bq0, c1, 0, 0, 0);
    c1 = __builtin_amdgcn_mfma_f32_16x16x32_bf16(ak11, bq1, c1, 0, 0, 0);

    float4 k20 = *(const float4*)&k2[hb + j0 + 4 * g];
    float4 rn0 = *(const float4*)&rnc[hb + j0 + 4 * g];
    float4 k21 = *(const float4*)&k2[hb + j0 + 16 + 4 * g];
    float4 rn1 = *(const float4*)&rnc[hb + j0 + 16 + 4 * g];

    float s0 = score_fn(c0[0], q2l + k20.x) * rn0.x;
    float s1 = score_fn(c0[1], q2l + k20.y) * rn0.y;
    float s2 = score_fn(c0[2], q2l + k20.z) * rn0.z;
    float s3 = score_fn(c0[3], q2l + k20.w) * rn0.w;
    float s4 = score_fn(c1[0], q2l + k21.x) * rn1.x;
    float s5 = score_fn(c1[1], q2l + k21.y) * rn1.y;
    float s6 = score_fn(c1[2], q2l + k21.z) * rn1.z;
    float s7 = score_fn(c1[3], q2l + k21.w) * rn1.w;
    dacc += ((s0 + s1) + (s2 + s3)) + ((s4 + s5) + (s6 + s7));

    int pi[4];
    pi[0] = (int)cvtpk(s0, s1);
    pi[1] = (int)cvtpk(s2, s3);
    pi[2] = (int)cvtpk(s4, s5);
    pi[3] = (int)cvtpk(s6, s7);
    short8 pa = *(short8*)pi;

#pragma unroll
    for (int t = 0; t < 4; ++t) {
      short8 bv = *(const short8*)&VTp[((size_t)bh * 64 + 16 * t + l15) * 1024 + j0 + 8 * g];
      o[t] = __builtin_amdgcn_mfma_f32_16x16x32_bf16(pa, bv, o[t], 0, 0, 0);
    }
  }

  // per-row partial sums over this wave's j-half
  dacc += __shfl_xor(dacc, 16);
  dacc += __shfl_xor(dacc, 32);
  if (l < 16) Ds[w][l] = dacc;
#pragma unroll
  for (int t = 0; t < 4; ++t)
#pragma unroll
    for (int r = 0; r < 4; ++r) Ls[w][l][t * 4 + r] = o[t][r];
  __syncthreads();

  // lower wave of each (wq) pair merges the two j-halves and writes
  if (w < 4) {
#pragma unroll
    for (int t = 0; t < 4; ++t) {
#pragma unroll
      for (int r = 0; r < 4; ++r) {
        float ov = o[t][r] + Ls[w + 4][l][t * 4 + r];
        float dv = Ds[w][4 * g + r] + Ds[w + 4][4 * g + r];
        int m = b * 1024 + it0 + 4 * g + r;
        int n = h * 64 + t * 16 + l15;
        AO[(size_t)m * 1024 + n] = f2bf(ov / dv);
      }
    }
  }
}

// ---------------------------------------------------------------------------
extern "C" void kernel_launch(void* const* d_in, const int* in_sizes, int n_in,
                              void* d_out, int out_size, void* d_ws, size_t ws_size,
                              hipStream_t stream) {
  const float* x  = (const float*)d_in[0];
  const float* WQ = (const float*)d_in[1];
  const float* bQ = (const float*)d_in[2];
  const float* WK = (const float*)d_in[3];
  const float* bK = (const float*)d_in[4];
  const float* WV = (const float*)d_in[5];
  const float* bV = (const float*)d_in[6];
  const float* WO = (const float*)d_in[7];
  const float* bO = (const float*)d_in[8];

  char* base = (char*)d_ws;
  unsigned short* xb  = (unsigned short*)(base);
  unsigned short* WQT = (unsigned short*)(base + (4u  << 20));
  unsigned short* WKT = (unsigned short*)(base + (6u  << 20));
  unsigned short* WVT = (unsigned short*)(base + (8u  << 20));
  unsigned short* WOT = (unsigned short*)(base + (10u << 20));
  unsigned short* Qb  = (unsigned short*)(base + (12u << 20));
  unsigned short* Kb  = (unsigned short*)(base + (16u << 20));
  unsigned short* VTp = (unsigned short*)(base + (20u << 20));
  unsigned short* AOb = (unsigned short*)(base + (24u << 20));
  float* q2  = (float*)(base + (28u << 20));
  float* k2  = (float*)(base + (28u << 20) + (128u << 10));
  float* rnc = (float*)(base + (28u << 20) + (256u << 10));

  cvt_f32_bf16<<<2048, 256, 0, stream>>>(x, xb);
  wtrans4<<<dim3(32, 32, 4), 256, 0, stream>>>(WQ, WK, WV, WO, WQT, WKT, WVT, WOT);

  // fused Q,K,V projections (V written k-permuted-transposed)
  gemm_st<<<dim3(32, 16, 3), 256, 0, stream>>>(xb, WQT, WKT, WVT, bQ, bK, bV,
                                               Qb, Kb, VTp, 0, 0, 1);

  sqnorm<<<dim3(128, 2), 256, 0, stream>>>(Qb, Kb, q2, k2);
  colsum_mfma<<<dim3(32, 16), 512, 0, stream>>>(Qb, Kb, q2, k2, rnc);
  attn_mfma<<<dim3(32, 16), 512, 0, stream>>>(Qb, Kb, VTp, q2, k2, rnc, AOb);

  // output projection
  gemm_st<<<dim3(32, 16, 1), 256, 0, stream>>>(AOb, WOT, WOT, WOT, bO, bO, bO,
                                               d_out, d_out, d_out, 2, 2, 2);
}